// Round 2
// baseline (179.851 us; speedup 1.0000x reference)
//
#include <hip/hip_runtime.h>

#define ECE_BINS 20
#define BLOCK    256
#define GRID     2048   // 8 blocks/CU x 256 CUs: exact residency, no tail

// clang-native vector types: __builtin_nontemporal_load requires these
// (HIP's float4/int4 are wrapper classes the builtin rejects).
typedef float vfloat4 __attribute__((ext_vector_type(4)));
typedef int   vint4   __attribute__((ext_vector_type(4)));

// Single fused kernel.
// Main loop: per-thread PRIVATE LDS bin columns, non-atomic RMW.
// s[b*256+tid]: bank = tid%32 for ANY bin -> conflict-free, no atomics
// (R2: LDS atomics lane-serialize ~190cyc; R5: global-atomic storm ~55us).
// Epilogue reduce uses ROTATED indexing — naive stride-32 row-sum is a
// 64-way bank conflict (R5 counter: 1.15M conflict cycles).
// LDS = 20480 B exactly -> 8 blocks/CU (160 KiB / 20 KiB), 32 waves/CU.
//
// Fusion: last-block-done ticket replaces the former ece_pass2 launch.
// Writer side: __syncthreads (partials stored) -> tid0 __threadfence
// (release: write back XCD L2) -> acq_rel agent-scope atomic ticket.
// Reader side: acquire via the atomic + __threadfence so the last block
// cannot read poison-stale partials lines from its own XCD's L2.
__global__ __launch_bounds__(BLOCK) void ece_fused(
    const vfloat4* __restrict__ conf,
    const vint4*   __restrict__ corr,
    float* __restrict__ partials,       // [GRID][ECE_BINS]
    unsigned int* __restrict__ counter, // zeroed by host-side memset
    float* __restrict__ out,
    int n4, float invN)
{
    __shared__ float s[ECE_BINS * BLOCK];   // 20480 B exactly
    __shared__ unsigned int s_ticket;

    const int tid = threadIdx.x;

    #pragma unroll
    for (int b = 0; b < ECE_BINS; ++b) s[b * BLOCK + tid] = 0.0f;
    // no barrier: columns are thread-private

    const int idx    = blockIdx.x * BLOCK + tid;
    const int stride = GRID * BLOCK;
    for (int i = idx; i < n4; i += stride) {
        vfloat4 c = __builtin_nontemporal_load(&conf[i]);  // streamed once
        vint4   k = __builtin_nontemporal_load(&corr[i]);
        int b0 = min((int)(c.x * 20.0f), ECE_BINS - 1);
        s[b0 * BLOCK + tid] += c.x - (float)k.x;
        int b1 = min((int)(c.y * 20.0f), ECE_BINS - 1);
        s[b1 * BLOCK + tid] += c.y - (float)k.y;
        int b2 = min((int)(c.z * 20.0f), ECE_BINS - 1);
        s[b2 * BLOCK + tid] += c.z - (float)k.z;
        int b3 = min((int)(c.w * 20.0f), ECE_BINS - 1);
        s[b3 * BLOCK + tid] += c.w - (float)k.w;
    }
    __syncthreads();

    // stage 1: 160 threads sum 32 columns each, rotated -> all 32 banks busy
    float a = 0.0f;
    if (tid < ECE_BINS * 8) {
        const int base = (tid >> 3) * BLOCK + (tid & 7) * 32;
        #pragma unroll
        for (int j = 0; j < 32; ++j) {
            int jj = (j + tid) & 31;
            a += s[base + jj];
        }
    }
    __syncthreads();
    if (tid < ECE_BINS * 8) s[tid] = a;   // overlay scratch, barrier-separated
    __syncthreads();

    // stage 2: 20 threads sum 8 partials, rotated -> one row per block
    if (tid < ECE_BINS) {
        float t = 0.0f;
        #pragma unroll
        for (int j = 0; j < 8; ++j) {
            int jj = (j + tid) & 7;
            t += s[tid * 8 + jj];
        }
        partials[blockIdx.x * ECE_BINS + tid] = t;
    }

    // ---- last-block-done ticket (replaces the former pass2 launch) ----
    __syncthreads();                       // all partials stores issued
    if (tid == 0) {
        __threadfence();                   // release: write back XCD L2
        s_ticket = __hip_atomic_fetch_add(counter, 1u, __ATOMIC_ACQ_REL,
                                          __HIP_MEMORY_SCOPE_AGENT);
    }
    __syncthreads();
    if (s_ticket != GRID - 1) return;      // uniform: all threads agree

    // last block: final reduce of [GRID][20] partials (164 KB, L2/L3-hot)
    __threadfence();                       // acquire: invalidate stale lines

    float acc[ECE_BINS];
    #pragma unroll
    for (int b = 0; b < ECE_BINS; ++b) acc[b] = 0.0f;

    const vfloat4* p4 = (const vfloat4*)partials;  // rows of 20 = 5 x float4
    for (int row = tid; row < GRID; row += BLOCK) {
        const vfloat4* r = p4 + row * 5;
        #pragma unroll
        for (int q = 0; q < 5; ++q) {
            vfloat4 v = r[q];
            acc[q * 4 + 0] += v.x;
            acc[q * 4 + 1] += v.y;
            acc[q * 4 + 2] += v.z;
            acc[q * 4 + 3] += v.w;
        }
    }
    #pragma unroll
    for (int b = 0; b < ECE_BINS; ++b) s[b * BLOCK + tid] = acc[b];
    __syncthreads();

    float a2 = 0.0f;
    if (tid < ECE_BINS * 8) {
        const int base = (tid >> 3) * BLOCK + (tid & 7) * 32;
        #pragma unroll
        for (int j = 0; j < 32; ++j) {
            int jj = (j + tid) & 31;
            a2 += s[base + jj];
        }
    }
    __syncthreads();
    if (tid < ECE_BINS * 8) s[tid] = a2;
    __syncthreads();

    if (tid < ECE_BINS) {
        float t2 = 0.0f;
        #pragma unroll
        for (int j = 0; j < 8; ++j) {
            int jj = (j + tid) & 7;
            t2 += s[tid * 8 + jj];
        }
        s[BLOCK + tid] = fabsf(t2);        // scratch past stage-1 region
    }
    __syncthreads();
    if (tid == 0) {
        float sum = 0.0f;
        #pragma unroll
        for (int b = 0; b < ECE_BINS; ++b) sum += s[BLOCK + b];
        out[0] = sum * invN;
    }
}

extern "C" void kernel_launch(void* const* d_in, const int* in_sizes, int n_in,
                              void* d_out, int out_size, void* d_ws, size_t ws_size,
                              hipStream_t stream) {
    const vfloat4* conf = (const vfloat4*)d_in[0];
    const vint4*   corr = (const vint4*)d_in[1];
    float* partials = (float*)d_ws;
    unsigned int* counter =
        (unsigned int*)((char*)d_ws + GRID * ECE_BINS * sizeof(float));
    float* out = (float*)d_out;

    int n  = in_sizes[0];
    int n4 = n / 4;  // N = 8388608, divisible by 4

    // ticket counter must start at 0 (workspace is poisoned between runs);
    // 4-byte async memset is graph-capture-safe (same path as harness fills)
    (void)hipMemsetAsync(counter, 0, sizeof(unsigned int), stream);
    ece_fused<<<GRID, BLOCK, 0, stream>>>(conf, corr, partials, counter, out,
                                          n4, 1.0f / (float)n);
}

// Round 3
// 96.441 us; speedup vs baseline: 1.8649x; 1.8649x over previous
//
#include <hip/hip_runtime.h>

#define ECE_BINS 20
#define BLOCK    256
#define GRID     2048   // 8 blocks/CU x 256 CUs: exact residency, no tail

// Pass 1: per-thread PRIVATE LDS bin columns, non-atomic RMW.
// s[b*256+tid]: bank = tid%32 for ANY bin -> conflict-free main loop, no
// atomics (R2: LDS atomics lane-serialize ~190cyc; R5: global-atomic storm
// costs ~55us). Epilogue reduce uses ROTATED indexing — the naive stride-32
// row-sum is a 64-way bank conflict (R5 counter: 1.15M conflict cycles).
// LDS is exactly 20480 B (stage-2 scratch overlays s) -> 8 blocks/CU.
//
// R1-R2 session note (fusion attempt, measured 179.9us): single-kernel
// last-block-done fusion is structurally unaffordable on MI355X — the
// producer-side __threadfence() is a per-block full-L2 writeback
// (buffer_wbl2), and with 256 MiB of dirty poison lines in L2 the 2048
// flushes collapse BW to 300 GB/s. Nontemporal loads also hurt (defeat
// L3 absorption), and the ticket scalar pushed LDS over the 512-B granule
// (20480->20992, residency 8->7/CU). Two-kernel split amortizes the
// cross-XCD visibility flush once at the kernel boundary. Do not re-fuse.
__global__ __launch_bounds__(BLOCK) void ece_pass1(
    const float4* __restrict__ conf,
    const int4*   __restrict__ corr,
    float* __restrict__ partials,   // [GRID][ECE_BINS]
    int n4)
{
    __shared__ float s[ECE_BINS * BLOCK];   // 20480 B exactly

    const int tid = threadIdx.x;

    #pragma unroll
    for (int b = 0; b < ECE_BINS; ++b) s[b * BLOCK + tid] = 0.0f;
    // no barrier: columns are thread-private

    const int idx    = blockIdx.x * BLOCK + tid;
    const int stride = GRID * BLOCK;
    for (int i = idx; i < n4; i += stride) {
        float4 c = conf[i];
        int4   k = corr[i];
        int b0 = min((int)(c.x * 20.0f), ECE_BINS - 1);
        s[b0 * BLOCK + tid] += c.x - (float)k.x;
        int b1 = min((int)(c.y * 20.0f), ECE_BINS - 1);
        s[b1 * BLOCK + tid] += c.y - (float)k.y;
        int b2 = min((int)(c.z * 20.0f), ECE_BINS - 1);
        s[b2 * BLOCK + tid] += c.z - (float)k.z;
        int b3 = min((int)(c.w * 20.0f), ECE_BINS - 1);
        s[b3 * BLOCK + tid] += c.w - (float)k.w;
    }
    __syncthreads();

    // stage 1: 160 threads sum 32 columns each, rotated -> all 32 banks busy
    float a = 0.0f;
    if (tid < ECE_BINS * 8) {
        const int base = (tid >> 3) * BLOCK + (tid & 7) * 32;
        #pragma unroll
        for (int j = 0; j < 32; ++j) {
            int jj = (j + tid) & 31;
            a += s[base + jj];
        }
    }
    __syncthreads();
    if (tid < ECE_BINS * 8) s[tid] = a;   // overlay scratch, barrier-separated
    __syncthreads();

    // stage 2: 20 threads sum 8 partials, rotated
    if (tid < ECE_BINS) {
        float t = 0.0f;
        #pragma unroll
        for (int j = 0; j < 8; ++j) {
            int jj = (j + tid) & 7;
            t += s[tid * 8 + jj];
        }
        partials[blockIdx.x * ECE_BINS + tid] = t;
    }
}

// Pass 2: reduce [nb][20] partials -> out = (1/N) * sum_b |bin_b|
__global__ __launch_bounds__(256) void ece_pass2(
    const float4* __restrict__ partials,  // rows of 20 floats = 5 x float4
    float* __restrict__ out,
    int nb, float invN)
{
    __shared__ float s[ECE_BINS * 256];

    const int tid = threadIdx.x;
    float acc[ECE_BINS];
    #pragma unroll
    for (int b = 0; b < ECE_BINS; ++b) acc[b] = 0.0f;

    for (int row = tid; row < nb; row += 256) {
        const float4* r = partials + row * 5;
        #pragma unroll
        for (int q = 0; q < 5; ++q) {
            float4 v = r[q];
            acc[q * 4 + 0] += v.x;
            acc[q * 4 + 1] += v.y;
            acc[q * 4 + 2] += v.z;
            acc[q * 4 + 3] += v.w;
        }
    }
    #pragma unroll
    for (int b = 0; b < ECE_BINS; ++b) s[b * 256 + tid] = acc[b];
    __syncthreads();

    float a = 0.0f;
    if (tid < ECE_BINS * 8) {
        const int base = (tid >> 3) * 256 + (tid & 7) * 32;
        #pragma unroll
        for (int j = 0; j < 32; ++j) {
            int jj = (j + tid) & 31;
            a += s[base + jj];
        }
    }
    __syncthreads();
    if (tid < ECE_BINS * 8) s[tid] = a;
    __syncthreads();

    if (tid < ECE_BINS) {
        float t = 0.0f;
        #pragma unroll
        for (int j = 0; j < 8; ++j) {
            int jj = (j + tid) & 7;
            t += s[tid * 8 + jj];
        }
        s[256 + tid] = fabsf(t);   // scratch slot, past stage-1 region
    }
    __syncthreads();
    if (tid == 0) {
        float sum = 0.0f;
        #pragma unroll
        for (int b = 0; b < ECE_BINS; ++b) sum += s[256 + b];
        out[0] = sum * invN;
    }
}

extern "C" void kernel_launch(void* const* d_in, const int* in_sizes, int n_in,
                              void* d_out, int out_size, void* d_ws, size_t ws_size,
                              hipStream_t stream) {
    const float4* conf = (const float4*)d_in[0];
    const int4*   corr = (const int4*)d_in[1];
    float* partials = (float*)d_ws;
    float* out      = (float*)d_out;

    int n  = in_sizes[0];
    int n4 = n / 4;  // N = 8388608, divisible by 4

    ece_pass1<<<GRID, BLOCK, 0, stream>>>(conf, corr, partials, n4);
    ece_pass2<<<1, 256, 0, stream>>>((const float4*)partials, out, GRID, 1.0f / (float)n);
}